// Round 9
// baseline (833.847 us; speedup 1.0000x reference)
//
#include <hip/hip_runtime.h>
#include <math.h>

// Problem constants
#define N_SP 96      // NV + NH
#define D_EMB 32
#define H_MLP 32
#define NPAIR 9216   // N*N
#define NBT 512      // B*T
#define HROWS 48     // rows per block (2 blocks per (b,t))

// float workspace offsets (floats)
#define WS_F_EMBI  0         // 96*32 (includes +b1)
#define WS_F_EMBJT 3072      // 32*97 (transposed [u][j], row stride 97)
#define WS_F_ALPHA 6176      // 96
#define WS_F_WG4   6272      // 9216*4  (forms 0-3, interleaved float4 per pair)
#define WS_F_WG1   43136     // 9216    (form 4 coef)

typedef __attribute__((ext_vector_type(8))) short bf16x8;
typedef __attribute__((ext_vector_type(4))) float f32x4;

// Fast gelu (tanh form) via v_exp_f32 + v_rcp_f32 (~3e-4 abs dev; msgs path only)
__device__ __forceinline__ float gelu_fast(float x){
  float x2 = x * x;
  float z  = x * fmaf(x2, -0.1029438824f, -2.3022077325f);
  float e  = __builtin_amdgcn_exp2f(z);
  return x * __builtin_amdgcn_rcpf(1.0f + e);
}

__device__ __forceinline__ short f2bf(float f){
  unsigned u = __builtin_bit_cast(unsigned, f);
  unsigned r = (u + 0x7FFFu + ((u >> 16) & 1u)) >> 16;
  return (short)r;
}

// ---- precompute: emb_i(+b1), emb_jT (stride 97), alpha ----
__global__ void pre1_kernel(const float* __restrict__ emb,
                            const float* __restrict__ w1, const float* __restrict__ b1,
                            const float* __restrict__ har,
                            float* __restrict__ wsf){
  const int n = blockIdx.x;
  const int t = threadIdx.x;           // 64 threads
  const int which = t >> 5, idx = t & 31;
  const float* e = emb + n * D_EMB;
  if (which == 0){
    float acc = b1[idx];
    #pragma unroll
    for (int u = 0; u < D_EMB; u++) acc = fmaf(e[u], w1[(2+u)*H_MLP + idx], acc);
    wsf[WS_F_EMBI + n*H_MLP + idx] = acc;
  } else {
    float acc = 0.f;
    #pragma unroll
    for (int u = 0; u < D_EMB; u++) acc = fmaf(e[u], w1[(2+D_EMB+u)*H_MLP + idx], acc);
    wsf[WS_F_EMBJT + idx*97 + n] = acc;   // transposed store [u][j], stride 97
  }
  if (t == 0){
    float h = har[n];
    float sp = (h > 20.f) ? h : log1pf(expf(h));
    wsf[WS_F_ALPHA + n] = sp + 0.01f;
  }
}

// ---- precompute wg = form_coefs * sigmoid(gates), repacked ----
__global__ void prewg_kernel(const float* __restrict__ fc, const float* __restrict__ fg,
                             float* __restrict__ wsf){
  int idx = blockIdx.x * 256 + threadIdx.x;
  if (idx < 5 * NPAIR){
    float g = 1.f / (1.f + expf(-fg[idx]));
    float v = fc[idx] * g;
    int f = idx / NPAIR;
    int p = idx - f * NPAIR;
    if (f < 4) wsf[WS_F_WG4 + 4*p + f] = v;
    else       wsf[WS_F_WG1 + p] = v;
  }
}

// Emulate numpy einsum f32 dot (SSE baseline, mul+add, 4x unroll, ascending
// chain), horizontal (acc0+acc1)+(acc2+acc3), then f32 division by sqrt(32).
// DO NOT TOUCH arithmetic — bit-matched to the np reference (topk razor rows).
__device__ __forceinline__ float np_score(const float* __restrict__ qi,
                                          const float* __restrict__ kT, int j){
  float acc[4];
  #pragma unroll
  for (int l = 0; l < 4; l++){
    float t = __fadd_rn(__fmul_rn(qi[4+l],  kT[(4+l)*97 + j]),
                        __fmul_rn(qi[l],    kT[(l)*97 + j]));
    t = __fadd_rn(__fmul_rn(qi[8+l],  kT[(8+l)*97 + j]), t);
    t = __fadd_rn(__fmul_rn(qi[12+l], kT[(12+l)*97 + j]), t);
    t = __fadd_rn(__fmul_rn(qi[16+l], kT[(16+l)*97 + j]), t);
    t = __fadd_rn(__fmul_rn(qi[20+l], kT[(20+l)*97 + j]), t);
    t = __fadd_rn(__fmul_rn(qi[24+l], kT[(24+l)*97 + j]), t);
    t = __fadd_rn(__fmul_rn(qi[28+l], kT[(28+l)*97 + j]), t);
    acc[l] = t;
  }
  float s01 = __fadd_rn(acc[0], acc[1]);
  float s23 = __fadd_rn(acc[2], acc[3]);
  return __fdiv_rn(__fadd_rn(s01, s23), 5.65685424949238019521f);
}

// ---- main: 2 blocks per (b,t); block owns 48 rows; fully fused per row ----
__global__ __launch_bounds__(512, 8) void main_kernel(
    const float* __restrict__ state, const float* __restrict__ rvec,
    const float* __restrict__ emb,
    const float* __restrict__ qwg, const float* __restrict__ qbg,
    const float* __restrict__ kwg, const float* __restrict__ kbg,
    const float* __restrict__ w1, const float* __restrict__ w2g,
    const float* __restrict__ b2g, const float* __restrict__ w3g,
    const float* __restrict__ b3g,
    const float* __restrict__ wsf,
    float* __restrict__ out_lr, float* __restrict__ out_attn){

  __shared__ __align__(16) float s_embi[HROWS*H_MLP];   // own rows only
  __shared__ float s_embjT[H_MLP*97];                   // [u][j], stride 97
  __shared__ __align__(16) float s_q[HROWS*D_EMB];      // own rows only
  __shared__ float s_kT[D_EMB*97];                      // [d][n], all n
  __shared__ float s_x[N_SP], s_hol[N_SP];
  __shared__ float s_wxi[H_MLP], s_wxj[H_MLP], s_b2[H_MLP], s_w3[H_MLP];

  const int tid  = threadIdx.x;
  const int bt   = blockIdx.x >> 1;
  const int roff = (blockIdx.x & 1) * HROWS;
  const int wave = tid >> 6, lane = tid & 63;

  for (int idx = tid; idx < HROWS*H_MLP; idx += 512)
    s_embi[idx] = wsf[WS_F_EMBI + roff*H_MLP + idx];
  for (int idx = tid; idx < H_MLP*97; idx += 512)
    s_embjT[idx] = wsf[WS_F_EMBJT + idx];
  if (tid < N_SP){
    float x = state[bt*N_SP + tid];
    s_x[tid] = x;
    float al = wsf[WS_F_ALPHA + tid];
    s_hol[tid] = x / (1.f + al * x);
  }
  if (tid >= 128 && tid < 160){
    int u = tid - 128;
    s_wxi[u] = w1[u];
    s_wxj[u] = w1[H_MLP + u];
    s_b2[u]  = b2g[u];
    s_w3[u]  = w3g[u];
  }
  __syncthreads();

  // Phase 0 (bit-exact feed of scores): kT for ALL n; q for own rows.
  for (int t = tid; t < N_SP*D_EMB; t += 512){
    const int n = t >> 5, d2 = t & 31;
    const float* e = emb + n*D_EMB;
    float ak = __fmul_rn(s_x[n], kwg[d2]);
    #pragma unroll
    for (int u = 0; u < D_EMB; u++)
      ak = fmaf(e[u], kwg[(1+u)*D_EMB + d2], ak);
    ak = __fadd_rn(ak, kbg[d2]);
    s_kT[d2*97 + n] = ak;
  }
  for (int t = tid; t < HROWS*D_EMB; t += 512){
    const int nl = t >> 5, d2 = t & 31;
    const int n  = roff + nl;
    const float* e = emb + n*D_EMB;
    float aq = __fmul_rn(s_x[n], qwg[d2]);
    #pragma unroll
    for (int u = 0; u < D_EMB; u++)
      aq = fmaf(e[u], qwg[(1+u)*D_EMB + d2], aq);
    aq = __fadd_rn(aq, qbg[d2]);
    s_q[t] = aq;
  }
  __syncthreads();   // s_kT/s_q visible to all waves; no barriers after this

  const float b3v = b3g[0];
  const float* wg4 = wsf + WS_F_WG4;
  const float* wg1 = wsf + WS_F_WG1;

  // w2^T as MFMA A-operand fragments. A[row=unit l15][k=kb+e] = w2[k][unit].
  const int l15 = lane & 15;
  const int g16 = lane >> 4;
  const int kb  = g16 * 8;
  bf16x8 w2f0, w2f1;
  #pragma unroll
  for (int e = 0; e < 8; e++){
    w2f0[e] = f2bf(w2g[(kb+e)*H_MLP + l15]);
    w2f1[e] = f2bf(w2g[(kb+e)*H_MLP + 16 + l15]);
  }
  float b2a[4], b2b[4], w3a[4], w3b[4];
  #pragma unroll
  for (int r = 0; r < 4; r++){
    b2a[r] = s_b2[4*g16 + r];      b2b[r] = s_b2[16 + 4*g16 + r];
    w3a[r] = s_w3[4*g16 + r];      w3b[r] = s_w3[16 + 4*g16 + r];
  }
  float wi[8], wj[8];
  #pragma unroll
  for (int e = 0; e < 8; e++){ wi[e] = s_wxi[kb+e]; wj[e] = s_wxj[kb+e]; }

  const float LOG2E = 1.44269504088896340736f;

  // Fused per-row loop: msgs (MFMA MLP, kept in regs) -> scores -> topk ->
  // softmax -> attn/lr. Wave owns 6 rows; fully wave-local, no barriers.
  for (int ii = 0; ii < 6; ii++){
    const int il = 6*wave + ii;          // local row 0..47
    const int i  = roff + il;
    const float xi = s_x[i];
    float base[8];
    #pragma unroll
    for (int e = 0; e < 8; e++)
      base[e] = fmaf(xi, wi[e], s_embi[il*H_MLP + kb + e]);

    float m0 = 0.f, m1 = 0.f;            // this lane's msg[i][lane], msg[i][64+lane]

    #pragma unroll
    for (int jb = 0; jb < 6; jb++){
      const int j0 = 16*jb;
      const int jl = j0 + l15;
      const float xj = s_x[jl];

      // early loads (all lanes; 4-way replicated, coalesced 256B segment)
      const int p = i*N_SP + jl;
      const float4 w4v = *(const float4*)&wg4[4*p];
      const float  w1v = wg1[p];
      const float  xjp = xj;
      const float  hjp = s_hol[jl];

      // h1 fragment (B-operand): lane holds h1[pair=l15][k=kb+e]
      bf16x8 hfrag;
      #pragma unroll
      for (int e = 0; e < 8; e++){
        float pre = fmaf(xj, wj[e], base[e] + s_embjT[(kb+e)*97 + jl]);
        hfrag[e] = f2bf(gelu_fast(pre));
      }

      f32x4 acc0 = {b2a[0], b2a[1], b2a[2], b2a[3]};
      f32x4 acc1 = {b2b[0], b2b[1], b2b[2], b2b[3]};
      acc0 = __builtin_amdgcn_mfma_f32_16x16x32_bf16(w2f0, hfrag, acc0, 0, 0, 0);
      acc1 = __builtin_amdgcn_mfma_f32_16x16x32_bf16(w2f1, hfrag, acc1, 0, 0, 0);

      float part = 0.f;
      #pragma unroll
      for (int r = 0; r < 4; r++) part = fmaf(gelu_fast(acc0[r]), w3a[r], part);
      #pragma unroll
      for (int r = 0; r < 4; r++) part = fmaf(gelu_fast(acc1[r]), w3b[r], part);
      part += __shfl_xor(part, 16);
      part += __shfl_xor(part, 32);
      // every lane: part = f4[pair 16jb+l15] - b3

      const float f4 = part + b3v;
      const float msg = w4v.x * xjp
                      + w4v.y * (xi*xjp)
                      + w4v.z * hjp
                      + w4v.w * (xi*hjp)
                      + w1v   * f4;
      // keep msg in the lane that phase-2 needs it in
      if (jb < 4){
        if (g16 == jb) m0 = msg;
      } else {
        if (g16 == jb - 4 && lane < 32) m1 = msg;
      }
    }

    // ---- score / topk / softmax / aggregate for row i (bit-exact path) ----
    const float* qi = s_q + il*D_EMB;
    float v0 = np_score(qi, s_kT, lane);
    float v1 = 0.f;
    if (lane < 32) v1 = np_score(qi, s_kT, 64 + lane);

    unsigned k0 = __builtin_bit_cast(unsigned, v0);
    k0 = (k0 >> 31) ? ~k0 : (k0 | 0x80000000u);
    unsigned k1 = 0u;
    if (lane < 32){
      unsigned u1 = __builtin_bit_cast(unsigned, v1);
      k1 = (u1 >> 31) ? ~u1 : (u1 | 0x80000000u);
    }

    // exact 8th-largest key via 32-step binary search on bits
    unsigned T = 0u;
    #pragma unroll
    for (int b = 31; b >= 0; --b){
      unsigned Tc = T | (1u << b);
      unsigned long long mm0 = __ballot(k0 >= Tc);
      unsigned long long mm1 = __ballot(k1 >= Tc);
      int cnt = __popcll(mm0) + __popcll(mm1);
      if (cnt >= 8) T = Tc;
    }
    unsigned uth = (T >> 31) ? (T ^ 0x80000000u) : ~T;
    const float thrf = __builtin_bit_cast(float, uth);

    float e0 = (k0 >= T) ? __builtin_amdgcn_exp2f(LOG2E*(v0 - thrf)) : 0.f;
    float e1 = 0.f;
    if (lane < 32 && k1 >= T) e1 = __builtin_amdgcn_exp2f(LOG2E*(v1 - thrf));

    float num = e0 * m0;
    if (lane < 32) num += e1 * m1;
    float den = e0 + e1;
    #pragma unroll
    for (int off = 32; off; off >>= 1){
      den += __shfl_xor(den, off);
      num += __shfl_xor(num, off);
    }
    float inv = 1.0f / den;
    float* arow = out_attn + (size_t)(bt*N_SP + i) * N_SP;
    arow[lane] = e0 * inv;
    if (lane < 32) arow[64 + lane] = e1 * inv;
    if (lane == 0) out_lr[bt*N_SP + i] = rvec[i] + num * inv;
  }
}

extern "C" void kernel_launch(void* const* d_in, const int* in_sizes, int n_in,
                              void* d_out, int out_size, void* d_ws, size_t ws_size,
                              hipStream_t stream){
  const float* state = (const float*)d_in[0];
  const float* emb   = (const float*)d_in[1];
  const float* qw    = (const float*)d_in[2];
  const float* qb    = (const float*)d_in[3];
  const float* kw    = (const float*)d_in[4];
  const float* kb    = (const float*)d_in[5];
  const float* fc    = (const float*)d_in[6];
  const float* fg    = (const float*)d_in[7];
  const float* har   = (const float*)d_in[8];
  const float* w1    = (const float*)d_in[9];
  const float* b1    = (const float*)d_in[10];
  const float* w2    = (const float*)d_in[11];
  const float* b2    = (const float*)d_in[12];
  const float* w3    = (const float*)d_in[13];
  const float* b3    = (const float*)d_in[14];
  const float* rv    = (const float*)d_in[15];

  float* wsf = (float*)d_ws;
  float* out_lr   = (float*)d_out;
  float* out_attn = out_lr + NBT * N_SP;

  hipLaunchKernelGGL(pre1_kernel, dim3(N_SP), dim3(64), 0, stream,
                     emb, w1, b1, har, wsf);
  hipLaunchKernelGGL(prewg_kernel, dim3(180), dim3(256), 0, stream, fc, fg, wsf);
  hipLaunchKernelGGL(main_kernel, dim3(2*NBT), dim3(512), 0, stream,
                     state, rv, emb, qw, qb, kw, kb, w1, w2, b2, w3, b3,
                     wsf, out_lr, out_attn);
}

// Round 10
// 431.104 us; speedup vs baseline: 1.9342x; 1.9342x over previous
//
#include <hip/hip_runtime.h>
#include <math.h>

// Problem constants
#define N_SP 96      // NV + NH
#define D_EMB 32
#define H_MLP 32
#define NPAIR 9216   // N*N
#define NBT 512      // B*T
#define HROWS 48     // rows per block (2 blocks per (b,t))

// float workspace offsets (floats)
#define WS_F_EMBI  0         // 96*32 (includes +b1)
#define WS_F_EMBJT 3072      // 32*97 (transposed [u][j], row stride 97)
#define WS_F_ALPHA 6176      // 96
#define WS_F_WG4   6272      // 9216*4  (forms 0-3, interleaved float4 per pair)
#define WS_F_WG1   43136     // 9216    (form 4 coef)

typedef __attribute__((ext_vector_type(8))) short bf16x8;
typedef __attribute__((ext_vector_type(4))) float f32x4;

// Fast gelu (tanh form) via v_exp_f32 + v_rcp_f32 (~3e-4 abs dev; msgs path only)
__device__ __forceinline__ float gelu_fast(float x){
  float x2 = x * x;
  float z  = x * fmaf(x2, -0.1029438824f, -2.3022077325f);
  float e  = __builtin_amdgcn_exp2f(z);
  return x * __builtin_amdgcn_rcpf(1.0f + e);
}

__device__ __forceinline__ short f2bf(float f){
  unsigned u = __builtin_bit_cast(unsigned, f);
  unsigned r = (u + 0x7FFFu + ((u >> 16) & 1u)) >> 16;
  return (short)r;
}

// ---- precompute: emb_i(+b1), emb_jT (stride 97), alpha ----
__global__ void pre1_kernel(const float* __restrict__ emb,
                            const float* __restrict__ w1, const float* __restrict__ b1,
                            const float* __restrict__ har,
                            float* __restrict__ wsf){
  const int n = blockIdx.x;
  const int t = threadIdx.x;           // 64 threads
  const int which = t >> 5, idx = t & 31;
  const float* e = emb + n * D_EMB;
  if (which == 0){
    float acc = b1[idx];
    #pragma unroll
    for (int u = 0; u < D_EMB; u++) acc = fmaf(e[u], w1[(2+u)*H_MLP + idx], acc);
    wsf[WS_F_EMBI + n*H_MLP + idx] = acc;
  } else {
    float acc = 0.f;
    #pragma unroll
    for (int u = 0; u < D_EMB; u++) acc = fmaf(e[u], w1[(2+D_EMB+u)*H_MLP + idx], acc);
    wsf[WS_F_EMBJT + idx*97 + n] = acc;   // transposed store [u][j], stride 97
  }
  if (t == 0){
    float h = har[n];
    float sp = (h > 20.f) ? h : log1pf(expf(h));
    wsf[WS_F_ALPHA + n] = sp + 0.01f;
  }
}

// ---- precompute wg = form_coefs * sigmoid(gates), repacked ----
__global__ void prewg_kernel(const float* __restrict__ fc, const float* __restrict__ fg,
                             float* __restrict__ wsf){
  int idx = blockIdx.x * 256 + threadIdx.x;
  if (idx < 5 * NPAIR){
    float g = 1.f / (1.f + expf(-fg[idx]));
    float v = fc[idx] * g;
    int f = idx / NPAIR;
    int p = idx - f * NPAIR;
    if (f < 4) wsf[WS_F_WG4 + 4*p + f] = v;
    else       wsf[WS_F_WG1 + p] = v;
  }
}

// Emulate numpy einsum f32 dot (SSE baseline, mul+add, 4x unroll, ascending
// chain), horizontal (acc0+acc1)+(acc2+acc3), then f32 division by sqrt(32).
// DO NOT TOUCH arithmetic — bit-matched to the np reference (topk razor rows).
__device__ __forceinline__ float np_score(const float* __restrict__ qi,
                                          const float* __restrict__ kT, int j){
  float acc[4];
  #pragma unroll
  for (int l = 0; l < 4; l++){
    float t = __fadd_rn(__fmul_rn(qi[4+l],  kT[(4+l)*97 + j]),
                        __fmul_rn(qi[l],    kT[(l)*97 + j]));
    t = __fadd_rn(__fmul_rn(qi[8+l],  kT[(8+l)*97 + j]), t);
    t = __fadd_rn(__fmul_rn(qi[12+l], kT[(12+l)*97 + j]), t);
    t = __fadd_rn(__fmul_rn(qi[16+l], kT[(16+l)*97 + j]), t);
    t = __fadd_rn(__fmul_rn(qi[20+l], kT[(20+l)*97 + j]), t);
    t = __fadd_rn(__fmul_rn(qi[24+l], kT[(24+l)*97 + j]), t);
    t = __fadd_rn(__fmul_rn(qi[28+l], kT[(28+l)*97 + j]), t);
    acc[l] = t;
  }
  float s01 = __fadd_rn(acc[0], acc[1]);
  float s23 = __fadd_rn(acc[2], acc[3]);
  return __fdiv_rn(__fadd_rn(s01, s23), 5.65685424949238019521f);
}

// ---- main: 2 blocks per (b,t); block owns 48 rows; fully fused per row ----
// launch_bounds(512,4): 128-VGPR cap. (512,8) strangled the allocator to 64
// and spilled 2.7 GB to scratch (R9 post-mortem) — do not raise again.
__global__ __launch_bounds__(512, 4) void main_kernel(
    const float* __restrict__ state, const float* __restrict__ rvec,
    const float* __restrict__ emb,
    const float* __restrict__ qwg, const float* __restrict__ qbg,
    const float* __restrict__ kwg, const float* __restrict__ kbg,
    const float* __restrict__ w1, const float* __restrict__ w2g,
    const float* __restrict__ b2g, const float* __restrict__ w3g,
    const float* __restrict__ b3g,
    const float* __restrict__ wsf,
    float* __restrict__ out_lr, float* __restrict__ out_attn){

  __shared__ __align__(16) float s_embi[HROWS*H_MLP];   // own rows only
  __shared__ float s_embjT[H_MLP*97];                   // [u][j], stride 97
  __shared__ __align__(16) float s_q[HROWS*D_EMB];      // own rows only
  __shared__ float s_kT[D_EMB*97];                      // [d][n], all n
  __shared__ float s_x[N_SP], s_hol[N_SP];
  __shared__ float s_wxi[H_MLP], s_wxj[H_MLP], s_b2[H_MLP], s_w3[H_MLP];

  const int tid  = threadIdx.x;
  const int bt   = blockIdx.x >> 1;
  const int roff = (blockIdx.x & 1) * HROWS;
  const int wave = tid >> 6, lane = tid & 63;

  for (int idx = tid; idx < HROWS*H_MLP; idx += 512)
    s_embi[idx] = wsf[WS_F_EMBI + roff*H_MLP + idx];
  for (int idx = tid; idx < H_MLP*97; idx += 512)
    s_embjT[idx] = wsf[WS_F_EMBJT + idx];
  if (tid < N_SP){
    float x = state[bt*N_SP + tid];
    s_x[tid] = x;
    float al = wsf[WS_F_ALPHA + tid];
    s_hol[tid] = x / (1.f + al * x);
  }
  if (tid >= 128 && tid < 160){
    int u = tid - 128;
    s_wxi[u] = w1[u];
    s_wxj[u] = w1[H_MLP + u];
    s_b2[u]  = b2g[u];
    s_w3[u]  = w3g[u];
  }
  __syncthreads();

  // Phase 0 (bit-exact feed of scores): kT for ALL n; q for own rows.
  for (int t = tid; t < N_SP*D_EMB; t += 512){
    const int n = t >> 5, d2 = t & 31;
    const float* e = emb + n*D_EMB;
    float ak = __fmul_rn(s_x[n], kwg[d2]);
    #pragma unroll
    for (int u = 0; u < D_EMB; u++)
      ak = fmaf(e[u], kwg[(1+u)*D_EMB + d2], ak);
    ak = __fadd_rn(ak, kbg[d2]);
    s_kT[d2*97 + n] = ak;
  }
  for (int t = tid; t < HROWS*D_EMB; t += 512){
    const int nl = t >> 5, d2 = t & 31;
    const int n  = roff + nl;
    const float* e = emb + n*D_EMB;
    float aq = __fmul_rn(s_x[n], qwg[d2]);
    #pragma unroll
    for (int u = 0; u < D_EMB; u++)
      aq = fmaf(e[u], qwg[(1+u)*D_EMB + d2], aq);
    aq = __fadd_rn(aq, qbg[d2]);
    s_q[t] = aq;
  }
  __syncthreads();   // s_kT/s_q visible to all waves; no barriers after this

  const float b3v = b3g[0];
  const float* wg4 = wsf + WS_F_WG4;
  const float* wg1 = wsf + WS_F_WG1;

  // w2^T as MFMA A-operand fragments. A[row=unit l15][k=kb+e] = w2[k][unit].
  const int l15 = lane & 15;
  const int g16 = lane >> 4;
  const int kb  = g16 * 8;
  bf16x8 w2f0, w2f1;
  #pragma unroll
  for (int e = 0; e < 8; e++){
    w2f0[e] = f2bf(w2g[(kb+e)*H_MLP + l15]);
    w2f1[e] = f2bf(w2g[(kb+e)*H_MLP + 16 + l15]);
  }
  float b2a[4], b2b[4], w3a[4], w3b[4];
  #pragma unroll
  for (int r = 0; r < 4; r++){
    b2a[r] = s_b2[4*g16 + r];      b2b[r] = s_b2[16 + 4*g16 + r];
    w3a[r] = s_w3[4*g16 + r];      w3b[r] = s_w3[16 + 4*g16 + r];
  }
  float wi[8], wj[8];
  #pragma unroll
  for (int e = 0; e < 8; e++){ wi[e] = s_wxi[kb+e]; wj[e] = s_wxj[kb+e]; }

  const float LOG2E = 1.44269504088896340736f;

  // Fused per-row loop: msgs (MFMA MLP, kept in regs) -> scores -> topk ->
  // softmax -> attn/lr. Wave owns 6 rows; fully wave-local, no barriers.
  for (int ii = 0; ii < 6; ii++){
    const int il = 6*wave + ii;          // local row 0..47
    const int i  = roff + il;
    const float xi = s_x[i];
    float base[8];
    #pragma unroll
    for (int e = 0; e < 8; e++)
      base[e] = fmaf(xi, wi[e], s_embi[il*H_MLP + kb + e]);

    float m0 = 0.f, m1 = 0.f;            // this lane's msg[i][lane], msg[i][64+lane]

    #pragma unroll
    for (int jb = 0; jb < 6; jb++){
      const int j0 = 16*jb;
      const int jl = j0 + l15;
      const float xj = s_x[jl];

      // early loads (all lanes; 4-way replicated, coalesced 256B segment)
      const int p = i*N_SP + jl;
      const float4 w4v = *(const float4*)&wg4[4*p];
      const float  w1v = wg1[p];
      const float  xjp = xj;
      const float  hjp = s_hol[jl];

      // h1 fragment (B-operand): lane holds h1[pair=l15][k=kb+e]
      bf16x8 hfrag;
      #pragma unroll
      for (int e = 0; e < 8; e++){
        float pre = fmaf(xj, wj[e], base[e] + s_embjT[(kb+e)*97 + jl]);
        hfrag[e] = f2bf(gelu_fast(pre));
      }

      f32x4 acc0 = {b2a[0], b2a[1], b2a[2], b2a[3]};
      f32x4 acc1 = {b2b[0], b2b[1], b2b[2], b2b[3]};
      acc0 = __builtin_amdgcn_mfma_f32_16x16x32_bf16(w2f0, hfrag, acc0, 0, 0, 0);
      acc1 = __builtin_amdgcn_mfma_f32_16x16x32_bf16(w2f1, hfrag, acc1, 0, 0, 0);

      float part = 0.f;
      #pragma unroll
      for (int r = 0; r < 4; r++) part = fmaf(gelu_fast(acc0[r]), w3a[r], part);
      #pragma unroll
      for (int r = 0; r < 4; r++) part = fmaf(gelu_fast(acc1[r]), w3b[r], part);
      part += __shfl_xor(part, 16);
      part += __shfl_xor(part, 32);
      // every lane: part = f4[pair 16jb+l15] - b3

      const float f4 = part + b3v;
      const float msg = w4v.x * xjp
                      + w4v.y * (xi*xjp)
                      + w4v.z * hjp
                      + w4v.w * (xi*hjp)
                      + w1v   * f4;
      // keep msg in the lane that phase-2 needs it in
      if (jb < 4){
        if (g16 == jb) m0 = msg;
      } else {
        if (g16 == jb - 4 && lane < 32) m1 = msg;
      }
    }

    // ---- score / topk / softmax / aggregate for row i (bit-exact path) ----
    const float* qi = s_q + il*D_EMB;
    float v0 = np_score(qi, s_kT, lane);
    float v1 = 0.f;
    if (lane < 32) v1 = np_score(qi, s_kT, 64 + lane);

    unsigned k0 = __builtin_bit_cast(unsigned, v0);
    k0 = (k0 >> 31) ? ~k0 : (k0 | 0x80000000u);
    unsigned k1 = 0u;
    if (lane < 32){
      unsigned u1 = __builtin_bit_cast(unsigned, v1);
      k1 = (u1 >> 31) ? ~u1 : (u1 | 0x80000000u);
    }

    // exact 8th-largest key via 32-step binary search on bits
    unsigned T = 0u;
    #pragma unroll
    for (int b = 31; b >= 0; --b){
      unsigned Tc = T | (1u << b);
      unsigned long long mm0 = __ballot(k0 >= Tc);
      unsigned long long mm1 = __ballot(k1 >= Tc);
      int cnt = __popcll(mm0) + __popcll(mm1);
      if (cnt >= 8) T = Tc;
    }
    unsigned uth = (T >> 31) ? (T ^ 0x80000000u) : ~T;
    const float thrf = __builtin_bit_cast(float, uth);

    float e0 = (k0 >= T) ? __builtin_amdgcn_exp2f(LOG2E*(v0 - thrf)) : 0.f;
    float e1 = 0.f;
    if (lane < 32 && k1 >= T) e1 = __builtin_amdgcn_exp2f(LOG2E*(v1 - thrf));

    float num = e0 * m0;
    if (lane < 32) num += e1 * m1;
    float den = e0 + e1;
    #pragma unroll
    for (int off = 32; off; off >>= 1){
      den += __shfl_xor(den, off);
      num += __shfl_xor(num, off);
    }
    float inv = 1.0f / den;
    float* arow = out_attn + (size_t)(bt*N_SP + i) * N_SP;
    arow[lane] = e0 * inv;
    if (lane < 32) arow[64 + lane] = e1 * inv;
    if (lane == 0) out_lr[bt*N_SP + i] = rvec[i] + num * inv;
  }
}

extern "C" void kernel_launch(void* const* d_in, const int* in_sizes, int n_in,
                              void* d_out, int out_size, void* d_ws, size_t ws_size,
                              hipStream_t stream){
  const float* state = (const float*)d_in[0];
  const float* emb   = (const float*)d_in[1];
  const float* qw    = (const float*)d_in[2];
  const float* qb    = (const float*)d_in[3];
  const float* kw    = (const float*)d_in[4];
  const float* kb    = (const float*)d_in[5];
  const float* fc    = (const float*)d_in[6];
  const float* fg    = (const float*)d_in[7];
  const float* har   = (const float*)d_in[8];
  const float* w1    = (const float*)d_in[9];
  const float* b1    = (const float*)d_in[10];
  const float* w2    = (const float*)d_in[11];
  const float* b2    = (const float*)d_in[12];
  const float* w3    = (const float*)d_in[13];
  const float* b3    = (const float*)d_in[14];
  const float* rv    = (const float*)d_in[15];

  float* wsf = (float*)d_ws;
  float* out_lr   = (float*)d_out;
  float* out_attn = out_lr + NBT * N_SP;

  hipLaunchKernelGGL(pre1_kernel, dim3(N_SP), dim3(64), 0, stream,
                     emb, w1, b1, har, wsf);
  hipLaunchKernelGGL(prewg_kernel, dim3(180), dim3(256), 0, stream, fc, fg, wsf);
  hipLaunchKernelGGL(main_kernel, dim3(2*NBT), dim3(512), 0, stream,
                     state, rv, emb, qw, qb, kw, kb, w1, w2, b2, w3, b3,
                     wsf, out_lr, out_attn);
}

// Round 11
// 300.330 us; speedup vs baseline: 2.7764x; 1.4354x over previous
//
#include <hip/hip_runtime.h>
#include <math.h>

// Problem constants
#define N_SP 96      // NV + NH
#define D_EMB 32
#define H_MLP 32
#define NPAIR 9216   // N*N
#define NBT 512      // B*T
#define HROWS 48     // rows per block (2 blocks per (b,t))

// float workspace offsets (floats)
#define WS_F_EMBI  0         // 96*32 (includes +b1)
#define WS_F_EMBJT 3072      // 32*97 (transposed [u][j], row stride 97)
#define WS_F_ALPHA 6176      // 96
#define WS_F_WG4   6272      // 9216*4  (forms 0-3, interleaved float4 per pair)
#define WS_F_WG1   43136     // 9216    (form 4 coef)

typedef __attribute__((ext_vector_type(8))) short bf16x8;
typedef __attribute__((ext_vector_type(4))) float f32x4;

// Fast gelu (tanh form) via v_exp_f32 + v_rcp_f32 (~3e-4 abs dev; msgs path only)
__device__ __forceinline__ float gelu_fast(float x){
  float x2 = x * x;
  float z  = x * fmaf(x2, -0.1029438824f, -2.3022077325f);
  float e  = __builtin_amdgcn_exp2f(z);
  return x * __builtin_amdgcn_rcpf(1.0f + e);
}

__device__ __forceinline__ short f2bf(float f){
  unsigned u = __builtin_bit_cast(unsigned, f);
  unsigned r = (u + 0x7FFFu + ((u >> 16) & 1u)) >> 16;
  return (short)r;
}

// ---- precompute: emb_i(+b1), emb_jT (stride 97), alpha ----
__global__ void pre1_kernel(const float* __restrict__ emb,
                            const float* __restrict__ w1, const float* __restrict__ b1,
                            const float* __restrict__ har,
                            float* __restrict__ wsf){
  const int n = blockIdx.x;
  const int t = threadIdx.x;           // 64 threads
  const int which = t >> 5, idx = t & 31;
  const float* e = emb + n * D_EMB;
  if (which == 0){
    float acc = b1[idx];
    #pragma unroll
    for (int u = 0; u < D_EMB; u++) acc = fmaf(e[u], w1[(2+u)*H_MLP + idx], acc);
    wsf[WS_F_EMBI + n*H_MLP + idx] = acc;
  } else {
    float acc = 0.f;
    #pragma unroll
    for (int u = 0; u < D_EMB; u++) acc = fmaf(e[u], w1[(2+D_EMB+u)*H_MLP + idx], acc);
    wsf[WS_F_EMBJT + idx*97 + n] = acc;   // transposed store [u][j], stride 97
  }
  if (t == 0){
    float h = har[n];
    float sp = (h > 20.f) ? h : log1pf(expf(h));
    wsf[WS_F_ALPHA + n] = sp + 0.01f;
  }
}

// ---- precompute wg = form_coefs * sigmoid(gates), repacked ----
__global__ void prewg_kernel(const float* __restrict__ fc, const float* __restrict__ fg,
                             float* __restrict__ wsf){
  int idx = blockIdx.x * 256 + threadIdx.x;
  if (idx < 5 * NPAIR){
    float g = 1.f / (1.f + expf(-fg[idx]));
    float v = fc[idx] * g;
    int f = idx / NPAIR;
    int p = idx - f * NPAIR;
    if (f < 4) wsf[WS_F_WG4 + 4*p + f] = v;
    else       wsf[WS_F_WG1 + p] = v;
  }
}

// Emulate numpy einsum f32 dot (SSE baseline, mul+add, 4x unroll, ascending
// chain), horizontal (acc0+acc1)+(acc2+acc3), then f32 division by sqrt(32).
// DO NOT TOUCH arithmetic — bit-matched to the np reference (topk razor rows).
__device__ __forceinline__ float np_score(const float* __restrict__ qi,
                                          const float* __restrict__ kT, int j){
  float acc[4];
  #pragma unroll
  for (int l = 0; l < 4; l++){
    float t = __fadd_rn(__fmul_rn(qi[4+l],  kT[(4+l)*97 + j]),
                        __fmul_rn(qi[l],    kT[(l)*97 + j]));
    t = __fadd_rn(__fmul_rn(qi[8+l],  kT[(8+l)*97 + j]), t);
    t = __fadd_rn(__fmul_rn(qi[12+l], kT[(12+l)*97 + j]), t);
    t = __fadd_rn(__fmul_rn(qi[16+l], kT[(16+l)*97 + j]), t);
    t = __fadd_rn(__fmul_rn(qi[20+l], kT[(20+l)*97 + j]), t);
    t = __fadd_rn(__fmul_rn(qi[24+l], kT[(24+l)*97 + j]), t);
    t = __fadd_rn(__fmul_rn(qi[28+l], kT[(28+l)*97 + j]), t);
    acc[l] = t;
  }
  float s01 = __fadd_rn(acc[0], acc[1]);
  float s23 = __fadd_rn(acc[2], acc[3]);
  return __fdiv_rn(__fadd_rn(s01, s23), 5.65685424949238019521f);
}

// ---- main: 2 blocks per (b,t); block owns 48 rows; fully fused per row ----
// NO min-waves clause: (512,8) and (512,4) both made the allocator halve the
// arch-VGPR budget (R9: 32, R10: 64) and spill GBs to scratch. Plain (512)
// lets it size to the code (R6/R7 precedent: spill-free).
__global__ __launch_bounds__(512) void main_kernel(
    const float* __restrict__ state, const float* __restrict__ rvec,
    const float* __restrict__ emb,
    const float* __restrict__ qwg, const float* __restrict__ qbg,
    const float* __restrict__ kwg, const float* __restrict__ kbg,
    const float* __restrict__ w1, const float* __restrict__ w2g,
    const float* __restrict__ b2g, const float* __restrict__ w3g,
    const float* __restrict__ b3g,
    const float* __restrict__ wsf,
    float* __restrict__ out_lr, float* __restrict__ out_attn){

  __shared__ __align__(16) float s_embi[HROWS*H_MLP];   // own rows only
  __shared__ float s_embjT[H_MLP*97];                   // [u][j], stride 97
  __shared__ __align__(16) float s_q[HROWS*D_EMB];      // own rows only
  __shared__ float s_kT[D_EMB*97];                      // [d][n], all n
  __shared__ float s_x[N_SP], s_hol[N_SP];
  __shared__ float s_wxi[H_MLP], s_wxj[H_MLP], s_b2[H_MLP], s_w3[H_MLP];

  const int tid  = threadIdx.x;
  const int bt   = blockIdx.x >> 1;
  const int roff = (blockIdx.x & 1) * HROWS;
  const int wave = tid >> 6, lane = tid & 63;

  for (int idx = tid; idx < HROWS*H_MLP; idx += 512)
    s_embi[idx] = wsf[WS_F_EMBI + roff*H_MLP + idx];
  for (int idx = tid; idx < H_MLP*97; idx += 512)
    s_embjT[idx] = wsf[WS_F_EMBJT + idx];
  if (tid < N_SP){
    float x = state[bt*N_SP + tid];
    s_x[tid] = x;
    float al = wsf[WS_F_ALPHA + tid];
    s_hol[tid] = x / (1.f + al * x);
  }
  if (tid >= 128 && tid < 160){
    int u = tid - 128;
    s_wxi[u] = w1[u];
    s_wxj[u] = w1[H_MLP + u];
    s_b2[u]  = b2g[u];
    s_w3[u]  = w3g[u];
  }
  __syncthreads();

  // Phase 0 (bit-exact feed of scores): kT for ALL n; q for own rows.
  for (int t = tid; t < N_SP*D_EMB; t += 512){
    const int n = t >> 5, d2 = t & 31;
    const float* e = emb + n*D_EMB;
    float ak = __fmul_rn(s_x[n], kwg[d2]);
    #pragma unroll
    for (int u = 0; u < D_EMB; u++)
      ak = fmaf(e[u], kwg[(1+u)*D_EMB + d2], ak);
    ak = __fadd_rn(ak, kbg[d2]);
    s_kT[d2*97 + n] = ak;
  }
  for (int t = tid; t < HROWS*D_EMB; t += 512){
    const int nl = t >> 5, d2 = t & 31;
    const int n  = roff + nl;
    const float* e = emb + n*D_EMB;
    float aq = __fmul_rn(s_x[n], qwg[d2]);
    #pragma unroll
    for (int u = 0; u < D_EMB; u++)
      aq = fmaf(e[u], qwg[(1+u)*D_EMB + d2], aq);
    aq = __fadd_rn(aq, qbg[d2]);
    s_q[t] = aq;
  }
  __syncthreads();   // s_kT/s_q visible to all waves; no barriers after this

  const float b3v = b3g[0];
  const float* wg4 = wsf + WS_F_WG4;
  const float* wg1 = wsf + WS_F_WG1;

  // w2^T as MFMA A-operand fragments. A[row=unit l15][k=kb+e] = w2[k][unit].
  // These are global+convert — keep register-resident. Everything else
  // (wxi/wxj/b2/w3) is read from LDS at use so the allocator can
  // rematerialize instead of spilling to scratch.
  const int l15 = lane & 15;
  const int g16 = lane >> 4;
  const int kb  = g16 * 8;
  bf16x8 w2f0, w2f1;
  #pragma unroll
  for (int e = 0; e < 8; e++){
    w2f0[e] = f2bf(w2g[(kb+e)*H_MLP + l15]);
    w2f1[e] = f2bf(w2g[(kb+e)*H_MLP + 16 + l15]);
  }

  const float LOG2E = 1.44269504088896340736f;

  // Fused per-row loop: msgs (MFMA MLP, kept in regs) -> scores -> topk ->
  // softmax -> attn/lr. Wave owns 6 rows; fully wave-local, no barriers.
  for (int ii = 0; ii < 6; ii++){
    const int il = 6*wave + ii;          // local row 0..47
    const int i  = roff + il;
    const float xi = s_x[i];
    float base[8];
    #pragma unroll
    for (int e = 0; e < 8; e++)
      base[e] = fmaf(xi, s_wxi[kb+e], s_embi[il*H_MLP + kb + e]);

    float m0 = 0.f, m1 = 0.f;            // this lane's msg[i][lane], msg[i][64+lane]

    #pragma unroll
    for (int jb = 0; jb < 6; jb++){
      const int j0 = 16*jb;
      const int jl = j0 + l15;
      const float xj = s_x[jl];

      // early loads (all lanes; 4-way replicated, coalesced 256B segment)
      const int p = i*N_SP + jl;
      const float4 w4v = *(const float4*)&wg4[4*p];
      const float  w1v = wg1[p];
      const float  hjp = s_hol[jl];

      // h1 fragment (B-operand): lane holds h1[pair=l15][k=kb+e]
      bf16x8 hfrag;
      #pragma unroll
      for (int e = 0; e < 8; e++){
        float pre = fmaf(xj, s_wxj[kb+e], base[e] + s_embjT[(kb+e)*97 + jl]);
        hfrag[e] = f2bf(gelu_fast(pre));
      }

      f32x4 acc0 = {s_b2[4*g16+0], s_b2[4*g16+1], s_b2[4*g16+2], s_b2[4*g16+3]};
      f32x4 acc1 = {s_b2[16+4*g16+0], s_b2[16+4*g16+1], s_b2[16+4*g16+2], s_b2[16+4*g16+3]};
      acc0 = __builtin_amdgcn_mfma_f32_16x16x32_bf16(w2f0, hfrag, acc0, 0, 0, 0);
      acc1 = __builtin_amdgcn_mfma_f32_16x16x32_bf16(w2f1, hfrag, acc1, 0, 0, 0);

      float part = 0.f;
      #pragma unroll
      for (int r = 0; r < 4; r++) part = fmaf(gelu_fast(acc0[r]), s_w3[4*g16+r], part);
      #pragma unroll
      for (int r = 0; r < 4; r++) part = fmaf(gelu_fast(acc1[r]), s_w3[16+4*g16+r], part);
      part += __shfl_xor(part, 16);
      part += __shfl_xor(part, 32);
      // every lane: part = f4[pair 16jb+l15] - b3

      const float f4 = part + b3v;
      const float msg = w4v.x * xj
                      + w4v.y * (xi*xj)
                      + w4v.z * hjp
                      + w4v.w * (xi*hjp)
                      + w1v   * f4;
      // keep msg in the lane that phase-2 needs it in
      if (jb < 4){
        if (g16 == jb) m0 = msg;
      } else {
        if (g16 == jb - 4 && lane < 32) m1 = msg;
      }
    }

    // ---- score / topk / softmax / aggregate for row i (bit-exact path) ----
    const float* qi = s_q + il*D_EMB;
    float v0 = np_score(qi, s_kT, lane);
    float v1 = 0.f;
    if (lane < 32) v1 = np_score(qi, s_kT, 64 + lane);

    unsigned k0 = __builtin_bit_cast(unsigned, v0);
    k0 = (k0 >> 31) ? ~k0 : (k0 | 0x80000000u);
    unsigned k1 = 0u;
    if (lane < 32){
      unsigned u1 = __builtin_bit_cast(unsigned, v1);
      k1 = (u1 >> 31) ? ~u1 : (u1 | 0x80000000u);
    }

    // exact 8th-largest key via 32-step binary search on bits
    unsigned T = 0u;
    #pragma unroll
    for (int b = 31; b >= 0; --b){
      unsigned Tc = T | (1u << b);
      unsigned long long mm0 = __ballot(k0 >= Tc);
      unsigned long long mm1 = __ballot(k1 >= Tc);
      int cnt = __popcll(mm0) + __popcll(mm1);
      if (cnt >= 8) T = Tc;
    }
    unsigned uth = (T >> 31) ? (T ^ 0x80000000u) : ~T;
    const float thrf = __builtin_bit_cast(float, uth);

    float e0 = (k0 >= T) ? __builtin_amdgcn_exp2f(LOG2E*(v0 - thrf)) : 0.f;
    float e1 = 0.f;
    if (lane < 32 && k1 >= T) e1 = __builtin_amdgcn_exp2f(LOG2E*(v1 - thrf));

    float num = e0 * m0;
    if (lane < 32) num += e1 * m1;
    float den = e0 + e1;
    #pragma unroll
    for (int off = 32; off; off >>= 1){
      den += __shfl_xor(den, off);
      num += __shfl_xor(num, off);
    }
    float inv = 1.0f / den;
    float* arow = out_attn + (size_t)(bt*N_SP + i) * N_SP;
    arow[lane] = e0 * inv;
    if (lane < 32) arow[64 + lane] = e1 * inv;
    if (lane == 0) out_lr[bt*N_SP + i] = rvec[i] + num * inv;
  }
}

extern "C" void kernel_launch(void* const* d_in, const int* in_sizes, int n_in,
                              void* d_out, int out_size, void* d_ws, size_t ws_size,
                              hipStream_t stream){
  const float* state = (const float*)d_in[0];
  const float* emb   = (const float*)d_in[1];
  const float* qw    = (const float*)d_in[2];
  const float* qb    = (const float*)d_in[3];
  const float* kw    = (const float*)d_in[4];
  const float* kb    = (const float*)d_in[5];
  const float* fc    = (const float*)d_in[6];
  const float* fg    = (const float*)d_in[7];
  const float* har   = (const float*)d_in[8];
  const float* w1    = (const float*)d_in[9];
  const float* b1    = (const float*)d_in[10];
  const float* w2    = (const float*)d_in[11];
  const float* b2    = (const float*)d_in[12];
  const float* w3    = (const float*)d_in[13];
  const float* b3    = (const float*)d_in[14];
  const float* rv    = (const float*)d_in[15];

  float* wsf = (float*)d_ws;
  float* out_lr   = (float*)d_out;
  float* out_attn = out_lr + NBT * N_SP;

  hipLaunchKernelGGL(pre1_kernel, dim3(N_SP), dim3(64), 0, stream,
                     emb, w1, b1, har, wsf);
  hipLaunchKernelGGL(prewg_kernel, dim3(180), dim3(256), 0, stream, fc, fg, wsf);
  hipLaunchKernelGGL(main_kernel, dim3(2*NBT), dim3(512), 0, stream,
                     state, rv, emb, qw, qb, kw, kb, w1, w2, b2, w3, b3,
                     wsf, out_lr, out_attn);
}

// Round 12
// 211.288 us; speedup vs baseline: 3.9465x; 1.4214x over previous
//
#include <hip/hip_runtime.h>
#include <math.h>

// Problem constants
#define N_SP 96      // NV + NH
#define D_EMB 32
#define H_MLP 32
#define NPAIR 9216   // N*N
#define NBT 512      // B*T
#define HROWS 48     // rows per block (2 blocks per (b,t))

// float workspace offsets (floats)
#define WS_F_EMBI  0         // 96*32 (includes +b1)
#define WS_F_EMBJT 3072      // 32*97 (transposed [u][j], row stride 97)
#define WS_F_ALPHA 6176      // 96
#define WS_F_WG4   6272      // 9216*4  (forms 0-3, interleaved float4 per pair)
#define WS_F_WG1   43136     // 9216    (form 4 coef)

typedef __attribute__((ext_vector_type(8))) short bf16x8;
typedef __attribute__((ext_vector_type(4))) float f32x4;

// Fast gelu (tanh form) via v_exp_f32 + v_rcp_f32 (~3e-4 abs dev; msgs path only)
__device__ __forceinline__ float gelu_fast(float x){
  float x2 = x * x;
  float z  = x * fmaf(x2, -0.1029438824f, -2.3022077325f);
  float e  = __builtin_amdgcn_exp2f(z);
  return x * __builtin_amdgcn_rcpf(1.0f + e);
}

__device__ __forceinline__ short f2bf(float f){
  unsigned u = __builtin_bit_cast(unsigned, f);
  unsigned r = (u + 0x7FFFu + ((u >> 16) & 1u)) >> 16;
  return (short)r;
}

// ---- precompute: emb_i(+b1), emb_jT (stride 97), alpha ----
__global__ void pre1_kernel(const float* __restrict__ emb,
                            const float* __restrict__ w1, const float* __restrict__ b1,
                            const float* __restrict__ har,
                            float* __restrict__ wsf){
  const int n = blockIdx.x;
  const int t = threadIdx.x;           // 64 threads
  const int which = t >> 5, idx = t & 31;
  const float* e = emb + n * D_EMB;
  if (which == 0){
    float acc = b1[idx];
    #pragma unroll
    for (int u = 0; u < D_EMB; u++) acc = fmaf(e[u], w1[(2+u)*H_MLP + idx], acc);
    wsf[WS_F_EMBI + n*H_MLP + idx] = acc;
  } else {
    float acc = 0.f;
    #pragma unroll
    for (int u = 0; u < D_EMB; u++) acc = fmaf(e[u], w1[(2+D_EMB+u)*H_MLP + idx], acc);
    wsf[WS_F_EMBJT + idx*97 + n] = acc;   // transposed store [u][j], stride 97
  }
  if (t == 0){
    float h = har[n];
    float sp = (h > 20.f) ? h : log1pf(expf(h));
    wsf[WS_F_ALPHA + n] = sp + 0.01f;
  }
}

// ---- precompute wg = form_coefs * sigmoid(gates), repacked ----
__global__ void prewg_kernel(const float* __restrict__ fc, const float* __restrict__ fg,
                             float* __restrict__ wsf){
  int idx = blockIdx.x * 256 + threadIdx.x;
  if (idx < 5 * NPAIR){
    float g = 1.f / (1.f + expf(-fg[idx]));
    float v = fc[idx] * g;
    int f = idx / NPAIR;
    int p = idx - f * NPAIR;
    if (f < 4) wsf[WS_F_WG4 + 4*p + f] = v;
    else       wsf[WS_F_WG1 + p] = v;
  }
}

// Emulate numpy einsum f32 dot (SSE baseline, mul+add, 4x unroll, ascending
// chain), horizontal (acc0+acc1)+(acc2+acc3), then f32 division by sqrt(32).
// DO NOT TOUCH arithmetic — bit-matched to the np reference (topk razor rows).
__device__ __forceinline__ float np_score(const float* __restrict__ qi,
                                          const float* __restrict__ kT, int j){
  float acc[4];
  #pragma unroll
  for (int l = 0; l < 4; l++){
    float t = __fadd_rn(__fmul_rn(qi[4+l],  kT[(4+l)*97 + j]),
                        __fmul_rn(qi[l],    kT[(l)*97 + j]));
    t = __fadd_rn(__fmul_rn(qi[8+l],  kT[(8+l)*97 + j]), t);
    t = __fadd_rn(__fmul_rn(qi[12+l], kT[(12+l)*97 + j]), t);
    t = __fadd_rn(__fmul_rn(qi[16+l], kT[(16+l)*97 + j]), t);
    t = __fadd_rn(__fmul_rn(qi[20+l], kT[(20+l)*97 + j]), t);
    t = __fadd_rn(__fmul_rn(qi[24+l], kT[(24+l)*97 + j]), t);
    t = __fadd_rn(__fmul_rn(qi[28+l], kT[(28+l)*97 + j]), t);
    acc[l] = t;
  }
  float s01 = __fadd_rn(acc[0], acc[1]);
  float s23 = __fadd_rn(acc[2], acc[3]);
  return __fdiv_rn(__fadd_rn(s01, s23), 5.65685424949238019521f);
}

// ---- main: 2 blocks per (b,t); block owns 48 rows; msgs staged in LDS ----
// R8 structure (proven spill-free, VGPR=40) with the global msg staging
// (178 MB HBM writes) replaced by LDS s_ms. One barrier between phases.
__global__ __launch_bounds__(512, 6) void main_kernel(
    const float* __restrict__ state, const float* __restrict__ rvec,
    const float* __restrict__ emb,
    const float* __restrict__ qwg, const float* __restrict__ qbg,
    const float* __restrict__ kwg, const float* __restrict__ kbg,
    const float* __restrict__ w1, const float* __restrict__ w2g,
    const float* __restrict__ b2g, const float* __restrict__ w3g,
    const float* __restrict__ b3g,
    const float* __restrict__ wsf,
    float* __restrict__ out_lr, float* __restrict__ out_attn){

  __shared__ __align__(16) float s_embi[HROWS*H_MLP];   // own rows only
  __shared__ float s_embjT[H_MLP*97];                   // [u][j], stride 97
  __shared__ __align__(16) float s_q[HROWS*D_EMB];      // own rows only
  __shared__ float s_kT[D_EMB*97];                      // [d][n], all n
  __shared__ float s_ms[HROWS*N_SP];                    // msgs staging (18 KB)
  __shared__ float s_x[N_SP], s_hol[N_SP];
  __shared__ float s_wxi[H_MLP], s_wxj[H_MLP], s_b2[H_MLP], s_w3[H_MLP];

  const int tid  = threadIdx.x;
  const int bt   = blockIdx.x >> 1;
  const int roff = (blockIdx.x & 1) * HROWS;
  const int wave = tid >> 6, lane = tid & 63;

  for (int idx = tid; idx < HROWS*H_MLP; idx += 512)
    s_embi[idx] = wsf[WS_F_EMBI + roff*H_MLP + idx];
  for (int idx = tid; idx < H_MLP*97; idx += 512)
    s_embjT[idx] = wsf[WS_F_EMBJT + idx];
  if (tid < N_SP){
    float x = state[bt*N_SP + tid];
    s_x[tid] = x;
    float al = wsf[WS_F_ALPHA + tid];
    s_hol[tid] = x / (1.f + al * x);
  }
  if (tid >= 128 && tid < 160){
    int u = tid - 128;
    s_wxi[u] = w1[u];
    s_wxj[u] = w1[H_MLP + u];
    s_b2[u]  = b2g[u];
    s_w3[u]  = w3g[u];
  }
  __syncthreads();

  // Phase 0 (bit-exact feed of scores): kT for ALL n; q for own rows.
  for (int t = tid; t < N_SP*D_EMB; t += 512){
    const int n = t >> 5, d2 = t & 31;
    const float* e = emb + n*D_EMB;
    float ak = __fmul_rn(s_x[n], kwg[d2]);
    #pragma unroll
    for (int u = 0; u < D_EMB; u++)
      ak = fmaf(e[u], kwg[(1+u)*D_EMB + d2], ak);
    ak = __fadd_rn(ak, kbg[d2]);
    s_kT[d2*97 + n] = ak;
  }
  for (int t = tid; t < HROWS*D_EMB; t += 512){
    const int nl = t >> 5, d2 = t & 31;
    const int n  = roff + nl;
    const float* e = emb + n*D_EMB;
    float aq = __fmul_rn(s_x[n], qwg[d2]);
    #pragma unroll
    for (int u = 0; u < D_EMB; u++)
      aq = fmaf(e[u], qwg[(1+u)*D_EMB + d2], aq);
    aq = __fadd_rn(aq, qbg[d2]);
    s_q[t] = aq;
  }

  const float b3v = b3g[0];
  const float* wg4 = wsf + WS_F_WG4;
  const float* wg1 = wsf + WS_F_WG1;

  // w2^T as MFMA A-operand fragments. A[row=unit l15][k=kb+e] = w2[k][unit].
  const int l15 = lane & 15;
  const int g16 = lane >> 4;
  const int kb  = g16 * 8;
  bf16x8 w2f0, w2f1;
  #pragma unroll
  for (int e = 0; e < 8; e++){
    w2f0[e] = f2bf(w2g[(kb+e)*H_MLP + l15]);
    w2f1[e] = f2bf(w2g[(kb+e)*H_MLP + 16 + l15]);
  }
  float b2a[4], b2b[4], w3a[4], w3b[4];
  #pragma unroll
  for (int r = 0; r < 4; r++){
    b2a[r] = s_b2[4*g16 + r];      b2b[r] = s_b2[16 + 4*g16 + r];
    w3a[r] = s_w3[4*g16 + r];      w3b[r] = s_w3[16 + 4*g16 + r];
  }
  float wi[8], wj[8];
  #pragma unroll
  for (int e = 0; e < 8; e++){ wi[e] = s_wxi[kb+e]; wj[e] = s_wxj[kb+e]; }
  __syncthreads();   // phase-0 stores visible

  // Phase 1: msgs via transposed-MFMA pairwise MLP -> LDS. Wave owns 6 rows.
  for (int ii = 0; ii < 6; ii++){
    const int il = 6*wave + ii;          // local row 0..47
    const int i  = roff + il;
    const float xi = s_x[i];
    float base[8];
    #pragma unroll
    for (int e = 0; e < 8; e++)
      base[e] = fmaf(xi, wi[e], s_embi[il*H_MLP + kb + e]);

    for (int jb = 0; jb < 6; jb++){
      const int j0 = 16*jb;
      const int jl = j0 + l15;
      const float xj = s_x[jl];

      // early loads for the msg tail (hide global latency under MFMA)
      float4 w4v = {0,0,0,0};
      float  w1v = 0.f, xjp = 0.f, hjp = 0.f;
      if (lane < 16){
        const int p = i*N_SP + j0 + lane;
        w4v = *(const float4*)&wg4[4*p];
        w1v = wg1[p];
        xjp = s_x[j0 + lane];
        hjp = s_hol[j0 + lane];
      }

      // h1 fragment (B-operand): lane holds h1[pair=l15][k=kb+e]
      bf16x8 hfrag;
      #pragma unroll
      for (int e = 0; e < 8; e++){
        float pre = fmaf(xj, wj[e], base[e] + s_embjT[(kb+e)*97 + jl]);
        hfrag[e] = f2bf(gelu_fast(pre));
      }

      f32x4 acc0 = {b2a[0], b2a[1], b2a[2], b2a[3]};
      f32x4 acc1 = {b2b[0], b2b[1], b2b[2], b2b[3]};
      acc0 = __builtin_amdgcn_mfma_f32_16x16x32_bf16(w2f0, hfrag, acc0, 0, 0, 0);
      acc1 = __builtin_amdgcn_mfma_f32_16x16x32_bf16(w2f1, hfrag, acc1, 0, 0, 0);

      float part = 0.f;
      #pragma unroll
      for (int r = 0; r < 4; r++) part = fmaf(gelu_fast(acc0[r]), w3a[r], part);
      #pragma unroll
      for (int r = 0; r < 4; r++) part = fmaf(gelu_fast(acc1[r]), w3b[r], part);
      part += __shfl_xor(part, 16);
      part += __shfl_xor(part, 32);

      if (lane < 16){
        const float f4 = part + b3v;
        const float msg = w4v.x * xjp
                        + w4v.y * (xi*xjp)
                        + w4v.z * hjp
                        + w4v.w * (xi*hjp)
                        + w1v   * f4;
        s_ms[il*N_SP + j0 + lane] = msg;
      }
    }
  }
  __syncthreads();   // s_ms visible across waves

  // Phase 2: np-exact scores -> radix-select exact 8th-largest threshold ->
  // softmax normalized by threshold (ratio-invariant) -> aggregate.
  const float LOG2E = 1.44269504088896340736f;

  for (int ip = 0; ip < 3; ip++){
    #pragma unroll
    for (int s = 0; s < 2; s++){
      const int il2 = wave + 16*ip + 8*s;
      const int i   = roff + il2;
      const float* qi = s_q + il2*D_EMB;
      float v0 = np_score(qi, s_kT, lane);
      float v1 = 0.f;
      if (lane < 32) v1 = np_score(qi, s_kT, 64 + lane);

      unsigned k0 = __builtin_bit_cast(unsigned, v0);
      k0 = (k0 >> 31) ? ~k0 : (k0 | 0x80000000u);
      unsigned k1 = 0u;
      if (lane < 32){
        unsigned u1 = __builtin_bit_cast(unsigned, v1);
        k1 = (u1 >> 31) ? ~u1 : (u1 | 0x80000000u);
      }

      // exact 8th-largest key via 32-step binary search on bits
      unsigned T = 0u;
      #pragma unroll
      for (int b = 31; b >= 0; --b){
        unsigned Tc = T | (1u << b);
        unsigned long long mm0 = __ballot(k0 >= Tc);
        unsigned long long mm1 = __ballot(k1 >= Tc);
        int cnt = __popcll(mm0) + __popcll(mm1);
        if (cnt >= 8) T = Tc;
      }
      unsigned uth = (T >> 31) ? (T ^ 0x80000000u) : ~T;
      const float thrf = __builtin_bit_cast(float, uth);

      float e0 = (k0 >= T) ? __builtin_amdgcn_exp2f(LOG2E*(v0 - thrf)) : 0.f;
      float e1 = 0.f;
      if (lane < 32 && k1 >= T) e1 = __builtin_amdgcn_exp2f(LOG2E*(v1 - thrf));

      const float* srow = s_ms + il2*N_SP;
      float num = e0 * srow[lane];
      if (lane < 32) num += e1 * srow[64 + lane];
      float den = e0 + e1;
      #pragma unroll
      for (int off = 32; off; off >>= 1){
        den += __shfl_xor(den, off);
        num += __shfl_xor(num, off);
      }
      float inv = 1.0f / den;
      float* arow = out_attn + (size_t)(bt*N_SP + i) * N_SP;
      arow[lane] = e0 * inv;
      if (lane < 32) arow[64 + lane] = e1 * inv;
      if (lane == 0) out_lr[bt*N_SP + i] = rvec[i] + num * inv;
    }
  }
}

extern "C" void kernel_launch(void* const* d_in, const int* in_sizes, int n_in,
                              void* d_out, int out_size, void* d_ws, size_t ws_size,
                              hipStream_t stream){
  const float* state = (const float*)d_in[0];
  const float* emb   = (const float*)d_in[1];
  const float* qw    = (const float*)d_in[2];
  const float* qb    = (const float*)d_in[3];
  const float* kw    = (const float*)d_in[4];
  const float* kb    = (const float*)d_in[5];
  const float* fc    = (const float*)d_in[6];
  const float* fg    = (const float*)d_in[7];
  const float* har   = (const float*)d_in[8];
  const float* w1    = (const float*)d_in[9];
  const float* b1    = (const float*)d_in[10];
  const float* w2    = (const float*)d_in[11];
  const float* b2    = (const float*)d_in[12];
  const float* w3    = (const float*)d_in[13];
  const float* b3    = (const float*)d_in[14];
  const float* rv    = (const float*)d_in[15];

  float* wsf = (float*)d_ws;
  float* out_lr   = (float*)d_out;
  float* out_attn = out_lr + NBT * N_SP;

  hipLaunchKernelGGL(pre1_kernel, dim3(N_SP), dim3(64), 0, stream,
                     emb, w1, b1, har, wsf);
  hipLaunchKernelGGL(prewg_kernel, dim3(180), dim3(256), 0, stream, fc, fg, wsf);
  hipLaunchKernelGGL(main_kernel, dim3(2*NBT), dim3(512), 0, stream,
                     state, rv, emb, qw, qb, kw, kb, w1, w2, b2, w3, b3,
                     wsf, out_lr, out_attn);
}